// Round 10
// baseline (317.475 us; speedup 1.0000x reference)
//
#include <hip/hip_runtime.h>
#include <math.h>

#define SEQ 2048
#define HID_DIM 2048
#define NH 16
#define NKV 4
#define HD 128
#define QS 3072   // fused qkv row stride (bf16): [q 2048 | k 512 | v 512]

typedef float  f4v  __attribute__((ext_vector_type(4)));
typedef __bf16 bf8v __attribute__((ext_vector_type(8)));
typedef __bf16 bf4v __attribute__((ext_vector_type(4)));
typedef __bf16 bf2v __attribute__((ext_vector_type(2)));

typedef __attribute__((address_space(1))) const void* gvp;
typedef __attribute__((address_space(3))) void*       svp;

__device__ __forceinline__ void gld16(const void* g, void* lds_wave_base) {
    __builtin_amdgcn_global_load_lds((gvp)g, (svp)lds_wave_base, 16, 0, 0);
}

__device__ __forceinline__ void wgb() {
    asm volatile("" ::: "memory");
    __builtin_amdgcn_s_barrier();
    asm volatile("" ::: "memory");
}
#define VMC(n) asm volatile("s_waitcnt vmcnt(" #n ")" ::: "memory")

// ---- single fused fp32 -> bf16 convert pass ----------------------------
__global__ __launch_bounds__(256)
void cvt_all(__bf16* __restrict__ Acat, __bf16* __restrict__ Wcat,
             __bf16* __restrict__ Wo,
             const float* __restrict__ hs, const float* __restrict__ mu,
             const float* __restrict__ wq, const float* __restrict__ wmq,
             const float* __restrict__ wk, const float* __restrict__ wmk,
             const float* __restrict__ wv, const float* __restrict__ wmv,
             const float* __restrict__ wo)
{
    int b = blockIdx.x;
    const float *s0, *s1; __bf16* dst;
    if (b < 8192)       { s0 = hs; s1 = mu;  dst = Acat; }
    else if (b < 16384) { s0 = wq; s1 = wmq; dst = Wcat;                            b -= 8192; }
    else if (b < 18432) { s0 = wk; s1 = wmk; dst = Wcat + (size_t)2048 * 4096;      b -= 16384; }
    else if (b < 20480) { s0 = wv; s1 = wmv; dst = Wcat + (size_t)2560 * 4096;      b -= 18432; }
    else {
        int i = (b - 20480) * 256 + threadIdx.x;
        float4 v = *reinterpret_cast<const float4*>(wo + (size_t)i * 4);
        *reinterpret_cast<bf4v*>(Wo + (size_t)i * 4) =
            bf4v{ (__bf16)v.x, (__bf16)v.y, (__bf16)v.z, (__bf16)v.w };
        return;
    }
    int i = b * 256 + threadIdx.x;
    int row = i >> 10, c = i & 1023;               // 1024 quads per dst row
    const float* s = (c < 512) ? s0 + ((size_t)row * 512 + c) * 4
                               : s1 + ((size_t)row * 512 + (c - 512)) * 4;
    float4 v = *reinterpret_cast<const float4*>(s);
    *reinterpret_cast<bf4v*>(dst + ((size_t)row * 1024 + c) * 4) =
        bf4v{ (__bf16)v.x, (__bf16)v.y, (__bf16)v.z, (__bf16)v.w };
}

// ---- 256x256 pipelined split-K NT GEMM, bf16 partials ------------------
// R9 schedule + counted-vmcnt staging (T4): stages issued one phase
// earlier, AFTER the MFMA consuming the buffer's last read (WAR safe via
// compiler lgkm drain before that MFMA). Body waits are VMC(4) — never 0:
// P2: stage B(t+2)->B0, VMC(4) drains t+1 (8 oldest), leaves B(t+2) flying
// P3: stage A(t+2)->A0 (after aHi-consuming MFMA)
// P6: stage B(t+3)->B1, VMC(4) drains t+2, leaves B(t+3) flying
// P7: stage A(t+3)->A1
// Stage->drain distance >= 3 phases (~1000cy) vs HBM ~900cy. Tail: VMC(0).
__device__ __forceinline__ void stage_half(
    const __bf16* __restrict__ g, int ldk, int row0, int ktile, int half,
    char* buf, int w, int sr, int sc)
{
#pragma unroll
    for (int j = 0; j < 2; ++j) {
        int sid = w * 2 + j;                       // 16 subtiles / half-tile
        int rb = half * 8 + (sid >> 1), cb = sid & 1;
        gld16(g + (size_t)(row0 + rb * 16 + sr) * ldk + ktile * 64 + cb * 32 + sc,
              buf + (rb * 2 + cb) * 1024);
    }
}
__device__ __forceinline__ void stage_tile(
    const __bf16* __restrict__ g, int ldk, int row0, int ktile,
    char* buf, int w, int sr, int sc)
{
    stage_half(g, ldk, row0, ktile, 0, buf, w, sr, sc);
    stage_half(g, ldk, row0, ktile, 1, buf, w, sr, sc);
}

#define LOAD_AF(DST, BUF, MTB) \
    _Pragma("unroll") for (int mt = 0; mt < 4; ++mt) \
    _Pragma("unroll") for (int ks = 0; ks < 2; ++ks) \
        DST[mt][ks] = *(const bf8v*)((BUF) + (((wm * 8 + (MTB) + mt) * 2 + ks) << 10) + frag_off);
#define LOAD_BF(DST, BUF, NTB) \
    _Pragma("unroll") for (int nt = 0; nt < 2; ++nt) \
    _Pragma("unroll") for (int ks = 0; ks < 2; ++ks) \
        DST[nt][ks] = *(const bf8v*)((BUF) + (((wn * 4 + (NTB) + nt) * 2 + ks) << 10) + frag_off);
#define MFMA_Q(MTB, NTB, AR, BR) \
    __builtin_amdgcn_s_setprio(1); \
    _Pragma("unroll") for (int mt = 0; mt < 4; ++mt) \
    _Pragma("unroll") for (int nt = 0; nt < 2; ++nt) \
    _Pragma("unroll") for (int ks = 0; ks < 2; ++ks) \
        acc[(MTB) + mt][(NTB) + nt] = __builtin_amdgcn_mfma_f32_16x16x32_bf16( \
            AR[mt][ks], BR[nt][ks], acc[(MTB) + mt][(NTB) + nt], 0, 0, 0); \
    __builtin_amdgcn_s_setprio(0);

__global__ __launch_bounds__(512, 2)
void gemm_nt_pl(const __bf16* __restrict__ A, const __bf16* __restrict__ B,
                __bf16* __restrict__ P, int M, int N, int K, int KS)
{
    __shared__ __align__(1024) char lds[131072];
    char* A0 = lds;
    char* A1 = lds + 32768;
    char* B0 = lds + 65536;
    char* B1 = lds + 98304;

    const int tid = threadIdx.x, lane = tid & 63, w = tid >> 6;
    const int wm = w >> 2, wn = w & 3;
    const int mm = lane & 15, quad = lane >> 4;

    // XCD-chunked swizzle (nwg % 8 == 0 for all launches here)
    const int nbx = gridDim.x, nby = gridDim.y;
    int flat = blockIdx.x + nbx * (blockIdx.y + nby * blockIdx.z);
    const int cpx = (nbx * nby * gridDim.z) >> 3;
    flat = (flat & 7) * cpx + (flat >> 3);
    const int bxi = flat % nbx, byi = (flat / nbx) % nby, bzi = flat / (nbx * nby);

    const int m0 = byi * 256, n0 = bxi * 256;
    const int kt0 = (bzi * KS) >> 6;
    const int T = KS >> 6;                          // K-tiles per block (>=4, even)

    const int sr = lane >> 2, sc = (lane & 3) * 8;  // staging lane offsets
    const int frag_off = (mm * 4 + quad) << 4;      // frag read offset in subtile

    f4v acc[8][4] = {};
    bf8v aLo[4][2], aHi[4][2], b01e[2][2], b01o[2][2], b23[2][2];

    // prologue: fully stage tiles kt0 (buf0), kt0+1 (buf1)
    stage_tile(A, K, m0, kt0,     A0, w, sr, sc);
    stage_tile(B, K, n0, kt0,     B0, w, sr, sc);
    stage_tile(A, K, m0, kt0 + 1, A1, w, sr, sc);
    stage_tile(B, K, n0, kt0 + 1, B1, w, sr, sc);
    VMC(8);                                         // drain tile kt0 (oldest 8)
    wgb();
    LOAD_AF(aLo, A0, 0)
    LOAD_BF(b01e, B0, 0)

    const int nbody = (T - 2) >> 1;
    for (int it = 0; it < nbody; ++it) {
        const int t2 = kt0 + 2 * it + 2, t3 = t2 + 1;
        // P1: rd b23(t); MFMA Q1(t)
        LOAD_BF(b23, B0, 2)
        MFMA_Q(0, 0, aLo, b01e)
        wgb();
        // P2: rd aHi(t); MFMA Q2(t) [consumes b23<-B0]; stage B(t+2)->B0;
        //     VMC(4) drains t+1, leaves B(t+2) in flight
        LOAD_AF(aHi, A0, 4)
        MFMA_Q(0, 2, aLo, b23)
        stage_tile(B, K, n0, t2, B0, w, sr, sc);
        VMC(4);
        wgb();
        // P3: rd aLo(t+1); MFMA Q3(t) [consumes aHi<-A0]; stage A(t+2)->A0
        LOAD_AF(aLo, A1, 0)
        MFMA_Q(4, 2, aHi, b23)
        stage_tile(A, K, m0, t2, A0, w, sr, sc);
        wgb();
        // P4: rd b01(t+1); MFMA Q4(t)
        LOAD_BF(b01o, B1, 0)
        MFMA_Q(4, 0, aHi, b01e)
        wgb();
        // P5: rd b23(t+1); MFMA Q1(t+1)
        LOAD_BF(b23, B1, 2)
        MFMA_Q(0, 0, aLo, b01o)
        wgb();
        // P6: rd aHi(t+1); MFMA Q2(t+1) [consumes b23<-B1]; stage B(t+3)->B1;
        //     VMC(4) drains t+2, leaves B(t+3) in flight
        LOAD_AF(aHi, A1, 4)
        MFMA_Q(0, 2, aLo, b23)
        stage_tile(B, K, n0, t3, B1, w, sr, sc);
        VMC(4);
        wgb();
        // P7: rd aLo(t+2); MFMA Q3(t+1) [consumes aHi<-A1]; stage A(t+3)->A1
        LOAD_AF(aLo, A0, 0)
        MFMA_Q(4, 2, aHi, b23)
        stage_tile(A, K, m0, t3, A1, w, sr, sc);
        wgb();
        // P8: rd b01(t+2); MFMA Q4(t+1)
        LOAD_BF(b01e, B0, 0)
        MFMA_Q(4, 0, aHi, b01o)
        wgb();
    }
    // tail: tiles T-2 (buf0), T-1 (buf1); no staging
    LOAD_BF(b23, B0, 2)
    MFMA_Q(0, 0, aLo, b01e)
    wgb();
    LOAD_AF(aHi, A0, 4)
    MFMA_Q(0, 2, aLo, b23)
    VMC(0);
    wgb();
    LOAD_AF(aLo, A1, 0)
    MFMA_Q(4, 2, aHi, b23)
    wgb();
    LOAD_BF(b01o, B1, 0)
    MFMA_Q(4, 0, aHi, b01e)
    wgb();
    LOAD_BF(b23, B1, 2)
    MFMA_Q(0, 0, aLo, b01o)
    wgb();
    LOAD_AF(aHi, A1, 4)
    MFMA_Q(0, 2, aLo, b23)
    wgb();
    MFMA_Q(4, 2, aHi, b23)
    MFMA_Q(4, 0, aHi, b01o)

    __bf16* Pz = P + (size_t)bzi * M * N;
#pragma unroll
    for (int mt = 0; mt < 8; ++mt)
#pragma unroll
        for (int nt = 0; nt < 4; ++nt)
#pragma unroll
            for (int r = 0; r < 4; ++r)
                Pz[(size_t)(m0 + wm * 128 + mt * 16 + quad * 4 + r) * N
                   + n0 + wn * 64 + nt * 16 + mm] = (__bf16)acc[mt][nt][r];
}

// ---- sum 4 bf16 partials -> fp32 out -----------------------------------
__global__ __launch_bounds__(256)
void add4(const __bf16* __restrict__ P, float* __restrict__ out, int n4)
{
    int i = blockIdx.x * 256 + threadIdx.x;
    if (i >= n4) return;
    float4 s = {0.f, 0.f, 0.f, 0.f};
#pragma unroll
    for (int z = 0; z < 4; ++z) {
        bf4v v = *reinterpret_cast<const bf4v*>(P + (size_t)z * n4 * 4 + (size_t)i * 4);
        s.x += (float)v[0]; s.y += (float)v[1]; s.z += (float)v[2]; s.w += (float)v[3];
    }
    *reinterpret_cast<float4*>(out + (size_t)i * 4) = s;
}

// ---- norm_rope fused with K-pack AND V-pack ----------------------------
__global__ __launch_bounds__(256)
void norm_rope_pk(__bf16* __restrict__ qkv /* p0, q in place */,
                  const __bf16* __restrict__ p1,
                  const float* __restrict__ qw, const float* __restrict__ kw,
                  __bf16* __restrict__ Kt, __bf16* __restrict__ Vt)
{
    const int s = blockIdx.x, hh = blockIdx.y * 4 + threadIdx.y, l = threadIdx.x;
    if (hh >= NH + NKV) {                          // ---- V path ----
        const int vh = hh - (NH + NKV);
        const int off = 2560 + vh * HD;
        const __bf16* p  = qkv + (size_t)s * QS + off;
        const __bf16* q1 = p1  + (size_t)s * QS + off;
        float x0 = (float)p[l]      + (float)q1[l];
        float x1 = (float)p[l + 64] + (float)q1[l + 64];
        char* tile = (char*)Vt + (size_t)(vh * 32 + (s >> 6)) * 16384;
        const int kc = (s >> 3) & 7, j = s & 7;
        const int d2 = l + 64;
        *reinterpret_cast<__bf16*>(tile + l  * 128 + ((kc ^ (l  & 7)) << 4) + j * 2) = (__bf16)x0;
        *reinterpret_cast<__bf16*>(tile + d2 * 128 + ((kc ^ (d2 & 7)) << 4) + j * 2) = (__bf16)x1;
        return;
    }
    const float* wn; float scale; int off;
    if (hh < NH) { off = hh * HD;               wn = qw; scale = 0.08838834764831845f; }
    else         { off = 2048 + (hh - NH) * HD; wn = kw; scale = 1.0f; }
    __bf16* p = qkv + (size_t)s * QS + off;
    const __bf16* q1 = p1 + (size_t)s * QS + off;
    float x0 = (float)p[l]      + (float)q1[l];
    float x1 = (float)p[l + 64] + (float)q1[l + 64];
    float ss = x0 * x0 + x1 * x1;
#pragma unroll
    for (int o = 32; o; o >>= 1) ss += __shfl_xor(ss, o);
    float inv = rsqrtf(ss * (1.0f / 128.0f) + 1e-6f);
    x0 *= inv * wn[l];
    x1 *= inv * wn[l + 64];
    float invf = exp2f(-(float)l * (13.287712379549449f / 64.0f));
    float ang  = (float)s * invf;
    float c, sn;
    sincosf(ang, &sn, &c);
    float y0 = (x0 * c - x1 * sn) * scale;
    float y1 = (x1 * c + x0 * sn) * scale;
    if (hh < NH) {
        p[l]      = (__bf16)y0;
        p[l + 64] = (__bf16)y1;
    } else {
        const int kh = hh - NH, key = s & 63;
        char* tile = (char*)Kt + (size_t)(kh * 32 + (s >> 6)) * 16384 + key * 256;
        const int sw = (key & 15) << 4;
        *reinterpret_cast<__bf16*>(tile + ((((l)      >> 3) << 4) ^ sw) + (l & 7) * 2) = (__bf16)y0;
        *reinterpret_cast<__bf16*>(tile + ((((l + 64) >> 3) << 4) ^ sw) + (l & 7) * 2) = (__bf16)y1;
    }
}

// ---- split-K MFMA flash attention, static-max softmax ------------------
// 8-wave blocks, 128 Q-rows, 128-kv-row staged unit, XCD-chunked swizzle.
// NEW (R10): split-K chunk 1024 -> 512 kv rows (grid x: 2->4). Max units
// per block drops 8 -> 4; worker blocks 384 -> 640 (~2.5/CU) -> load-
// balanced wall. Per-unit code unchanged (R5-verified).
__global__ __launch_bounds__(512)
void attn_split(const __bf16* __restrict__ qkv,
                const __bf16* __restrict__ Kt, const __bf16* __restrict__ Vt,
                __bf16* __restrict__ Op, float* __restrict__ Lp)
{
    __shared__ char Ks[32768];
    __shared__ char Vs[32768];
    __shared__ char Ps[8][2048];

    int flat = blockIdx.x + 4 * (blockIdx.y + 16 * blockIdx.z);   // 1024 blocks
    flat = (flat & 7) * 128 + (flat >> 3);
    const int c = flat & 3, qt = 15 - ((flat >> 2) & 15), h = flat >> 6;

    if (c * 4 > qt) return;
    const int kend = min(qt, c * 4 + 3);
    const int tid = threadIdx.x, lane = tid & 63, w = tid >> 6;
    const int mm = lane & 15, quad = lane >> 4;
    const int kh = h >> 2;

    bf8v aq[4];
    const __bf16* qbase = qkv + (size_t)(qt * 128 + w * 16 + mm) * QS + h * HD;
#pragma unroll
    for (int ks = 0; ks < 4; ++ks)
        aq[ks] = *reinterpret_cast<const bf8v*>(qbase + ks * 32 + quad * 8);

    float lp[4] = {};
    f4v oacc[8] = {};

    const char* kbase = (const char*)Kt + (size_t)(kh * 32) * 16384;
    const char* vbase = (const char*)Vt + (size_t)(kh * 32) * 16384;

    for (int tt = c * 4; tt <= kend; ++tt) {
        wgb();                                      // prev compute done (WAR)
#pragma unroll
        for (int j = 0; j < 4; ++j) {
            int chunk = w * 4 + j;                  // 32 chunks = 2 sub-tiles
            gld16(kbase + (size_t)tt * 32768 + chunk * 1024 + lane * 16,
                  Ks + chunk * 1024);
            gld16(vbase + (size_t)tt * 32768 + chunk * 1024 + lane * 16,
                  Vs + chunk * 1024);
        }
        VMC(0);
        wgb();

        const int nss = (tt == qt && w < 4) ? 1 : 2; // skip fully-masked sub
        for (int ss = 0; ss < nss; ++ss) {
            const char* Ksub = Ks + ss * 16384;
            const char* Vsub = Vs + ss * 16384;

            f4v s[4] = {};
#pragma unroll
            for (int ks = 0; ks < 4; ++ks)
#pragma unroll
                for (int c16 = 0; c16 < 4; ++c16) {
                    bf8v b = *reinterpret_cast<const bf8v*>(
                        Ksub + (c16 * 16 + mm) * 256 + (((ks * 4 + quad) ^ mm) << 4));
                    s[c16] = __builtin_amdgcn_mfma_f32_16x16x32_bf16(aq[ks], b, s[c16], 0, 0, 0);
                }
            if (tt == qt) {
#pragma unroll
                for (int c16 = 0; c16 < 4; ++c16)
#pragma unroll
                    for (int r = 0; r < 4; ++r)
                        if (ss * 64 + c16 * 16 + mm > w * 16 + quad * 4 + r)
                            s[c16][r] = -__builtin_inff();
            }
            float pr[4][4];
#pragma unroll
            for (int c16 = 0; c16 < 4; ++c16)
#pragma unroll
                for (int r = 0; r < 4; ++r) {
                    pr[c16][r] = __expf(s[c16][r]);
                    lp[r] += pr[c16][r];
                }
#pragma unroll
            for (int c16 = 0; c16 < 4; ++c16)
#pragma unroll
                for (int r = 0; r < 4; ++r) {
                    float mine  = pr[c16][r];
                    float other = __shfl_xor(mine, 1);
                    if ((mm & 1) == 0) {
                        int roww = quad * 4 + r;
                        int cc   = c16 * 2 + (mm >> 3);
                        *reinterpret_cast<bf2v*>(
                            &Ps[w][roww * 128 + ((cc ^ (roww & 7)) << 4) + (mm & 7) * 2]) =
                            bf2v{ (__bf16)mine, (__bf16)other };
                    }
                }
            bf8v pa[2];
#pragma unroll
            for (int kb = 0; kb < 2; ++kb)
                pa[kb] = *reinterpret_cast<const bf8v*>(
                    &Ps[w][mm * 128 + (((kb * 4 + quad) ^ (mm & 7)) << 4)]);
#pragma unroll
            for (int nb = 0; nb < 8; ++nb) {
                int d = nb * 16 + mm;
#pragma unroll
                for (int kb = 0; kb < 2; ++kb) {
                    bf8v bv = *reinterpret_cast<const bf8v*>(
                        Vsub + d * 128 + (((kb * 4 + quad) ^ (d & 7)) << 4));
                    oacc[nb] = __builtin_amdgcn_mfma_f32_16x16x32_bf16(pa[kb], bv, oacc[nb], 0, 0, 0);
                }
            }
        }
    }
#pragma unroll
    for (int off = 1; off < 16; off <<= 1)
#pragma unroll
        for (int r = 0; r < 4; ++r) lp[r] += __shfl_xor(lp[r], off);
#pragma unroll
    for (int r = 0; r < 4; ++r) {
        int row = qt * 128 + w * 16 + quad * 4 + r;
        size_t obase = ((size_t)(c * 16 + h) * SEQ + row) * HD;
#pragma unroll
        for (int nb = 0; nb < 8; ++nb)
            Op[obase + nb * 16 + mm] = (__bf16)oacc[nb][r];
        if (mm == 0)
            Lp[(size_t)(c * 16 + h) * SEQ + row] = lp[r];
    }
}

// ---- combine split-K partials -> ab (bf16 [row][h*128+d]) --------------
__global__ __launch_bounds__(256)
void combine(const __bf16* __restrict__ Op, const float* __restrict__ Lp,
             __bf16* __restrict__ ab)
{
    const int row = blockIdx.x, h = blockIdx.y * 4 + threadIdx.y, l = threadIdx.x;
    const int nch = (row >> 9) + 1;                // 512 kv rows per chunk
    float L = 0.f, a0 = 0.f, a1 = 0.f;
    for (int c = 0; c < nch; ++c) {
        L += Lp[(size_t)(c * 16 + h) * SEQ + row];
        bf2v p = *reinterpret_cast<const bf2v*>(
            Op + ((size_t)(c * 16 + h) * SEQ + row) * HD + 2 * l);
        a0 += (float)p[0];
        a1 += (float)p[1];
    }
    float inv = 1.f / L;
    *reinterpret_cast<bf2v*>(ab + (size_t)row * (NH * HD) + h * HD + 2 * l) =
        bf2v{ (__bf16)(a0 * inv), (__bf16)(a1 * inv) };
}

extern "C" void kernel_launch(void* const* d_in, const int* in_sizes, int n_in,
                              void* d_out, int out_size, void* d_ws, size_t ws_size,
                              hipStream_t stream)
{
    const float* hs  = (const float*)d_in[0];
    const float* mu  = (const float*)d_in[1];
    const float* wq  = (const float*)d_in[2];
    const float* wk  = (const float*)d_in[3];
    const float* wv  = (const float*)d_in[4];
    const float* wo  = (const float*)d_in[5];
    const float* wmq = (const float*)d_in[6];
    const float* wmk = (const float*)d_in[7];
    const float* wmv = (const float*)d_in[8];
    const float* qw  = (const float*)d_in[9];
    const float* kw  = (const float*)d_in[10];
    float* out = (float*)d_out;

    char* ws = (char*)d_ws;
    // phase 1 (projection):
    __bf16* Wcat = (__bf16*)(ws + 0);          // [3072,4096] 25.2 MB
    __bf16* Acat = (__bf16*)(ws + 25165824);   // [2048,4096] 16.8 MB
    __bf16* Wo   = (__bf16*)(ws + 41943040);   // [2048,2048]  8.4 MB
    __bf16* qkvp = (__bf16*)(ws + 50331648);   // 2x[2048,3072] bf16 partials
    __bf16* ab   = (__bf16*)(ws + 75497472);   // [2048,2048] bf16, peak 83.9 MB
    // phase 2 aliases (Wcat/Acat dead after QKV GEMM):
    __bf16* Ktl  = (__bf16*)(ws + 0);          // 2 MB
    __bf16* Vtl  = (__bf16*)(ws + 2097152);    // 2 MB
    __bf16* Opart= (__bf16*)(ws + 4194304);    // 4x16 chunk-images = 32 MB
    float*  Lpart= (float*) (ws + 37748736);   // 0.5 MB
    // phase 3 alias (attn scratch dead after combine):
    __bf16* outp = (__bf16*)(ws + 0);          // 4x[2048,2048] bf16 = 33.6 MB

    // single fused convert pass
    cvt_all<<<dim3(24576), 256, 0, stream>>>(Acat, Wcat, Wo,
                                             hs, mu, wq, wmq, wk, wmk, wv, wmv, wo);

    // QKV projection: 256^2 pipelined, split-K=2 -> 192 blocks (bf16 partials)
    gemm_nt_pl<<<dim3(QS / 256, SEQ / 256, 2), 512, 0, stream>>>(
        Acat, Wcat, qkvp, SEQ, QS, 2 * HID_DIM, HID_DIM);
    // norm+rope; q in place, k packed into Ktl, v packed into Vtl (all fused)
    norm_rope_pk<<<dim3(SEQ, 6), dim3(64, 4), 0, stream>>>(
        qkvp, qkvp + (size_t)SEQ * QS, qw, kw, Ktl, Vtl);
    // attention: 8-wave blocks, 128 Q-rows, split-K chunk = 512 kv rows
    attn_split<<<dim3(4, 16, NH), 512, 0, stream>>>(qkvp, Ktl, Vtl, Opart, Lpart);
    combine<<<dim3(SEQ, 4), dim3(64, 4), 0, stream>>>(Opart, Lpart, ab);
    // output projection: split-K=4 -> 256 blocks, bf16 partials + add pass
    gemm_nt_pl<<<dim3(HID_DIM / 256, SEQ / 256, 4), 512, 0, stream>>>(
        ab, Wo, outp, SEQ, HID_DIM, NH * HD, 512);
    add4<<<dim3((1024 * 1024 + 255) / 256), 256, 0, stream>>>(outp, out, 1024 * 1024);
}

// Round 12
// 308.451 us; speedup vs baseline: 1.0293x; 1.0293x over previous
//
#include <hip/hip_runtime.h>
#include <math.h>

#define SEQ 2048
#define HID_DIM 2048
#define NH 16
#define NKV 4
#define HD 128
#define QS 3072   // fused qkv row stride (bf16): [q 2048 | k 512 | v 512]

typedef float  f4v  __attribute__((ext_vector_type(4)));
typedef __bf16 bf8v __attribute__((ext_vector_type(8)));
typedef __bf16 bf4v __attribute__((ext_vector_type(4)));
typedef __bf16 bf2v __attribute__((ext_vector_type(2)));

typedef __attribute__((address_space(1))) const void* gvp;
typedef __attribute__((address_space(3))) void*       svp;

__device__ __forceinline__ void gld16(const void* g, void* lds_wave_base) {
    __builtin_amdgcn_global_load_lds((gvp)g, (svp)lds_wave_base, 16, 0, 0);
}

__device__ __forceinline__ void wgb() {
    asm volatile("" ::: "memory");
    __builtin_amdgcn_s_barrier();
    asm volatile("" ::: "memory");
}
#define VMC(n) asm volatile("s_waitcnt vmcnt(" #n ")" ::: "memory")

// ---- single fused fp32 -> bf16 convert pass ----------------------------
__global__ __launch_bounds__(256)
void cvt_all(__bf16* __restrict__ Acat, __bf16* __restrict__ Wcat,
             __bf16* __restrict__ Wo,
             const float* __restrict__ hs, const float* __restrict__ mu,
             const float* __restrict__ wq, const float* __restrict__ wmq,
             const float* __restrict__ wk, const float* __restrict__ wmk,
             const float* __restrict__ wv, const float* __restrict__ wmv,
             const float* __restrict__ wo)
{
    int b = blockIdx.x;
    const float *s0, *s1; __bf16* dst;
    if (b < 8192)       { s0 = hs; s1 = mu;  dst = Acat; }
    else if (b < 16384) { s0 = wq; s1 = wmq; dst = Wcat;                            b -= 8192; }
    else if (b < 18432) { s0 = wk; s1 = wmk; dst = Wcat + (size_t)2048 * 4096;      b -= 16384; }
    else if (b < 20480) { s0 = wv; s1 = wmv; dst = Wcat + (size_t)2560 * 4096;      b -= 18432; }
    else {
        int i = (b - 20480) * 256 + threadIdx.x;
        float4 v = *reinterpret_cast<const float4*>(wo + (size_t)i * 4);
        *reinterpret_cast<bf4v*>(Wo + (size_t)i * 4) =
            bf4v{ (__bf16)v.x, (__bf16)v.y, (__bf16)v.z, (__bf16)v.w };
        return;
    }
    int i = b * 256 + threadIdx.x;
    int row = i >> 10, c = i & 1023;               // 1024 quads per dst row
    const float* s = (c < 512) ? s0 + ((size_t)row * 512 + c) * 4
                               : s1 + ((size_t)row * 512 + (c - 512)) * 4;
    float4 v = *reinterpret_cast<const float4*>(s);
    *reinterpret_cast<bf4v*>(dst + ((size_t)row * 1024 + c) * 4) =
        bf4v{ (__bf16)v.x, (__bf16)v.y, (__bf16)v.z, (__bf16)v.w };
}

// ---- 256x256 pipelined split-K NT GEMM, bf16 partials ------------------
// R10 schedule (counted-vmcnt staging, VMC(4) body waits, never 0) + XCD
// swizzle. This GEMM has plateaued 68-73 us across 5 structural variants
// at this shape (m102 shape-curve regime) — treated as settled.
__device__ __forceinline__ void stage_half(
    const __bf16* __restrict__ g, int ldk, int row0, int ktile, int half,
    char* buf, int w, int sr, int sc)
{
#pragma unroll
    for (int j = 0; j < 2; ++j) {
        int sid = w * 2 + j;                       // 16 subtiles / half-tile
        int rb = half * 8 + (sid >> 1), cb = sid & 1;
        gld16(g + (size_t)(row0 + rb * 16 + sr) * ldk + ktile * 64 + cb * 32 + sc,
              buf + (rb * 2 + cb) * 1024);
    }
}
__device__ __forceinline__ void stage_tile(
    const __bf16* __restrict__ g, int ldk, int row0, int ktile,
    char* buf, int w, int sr, int sc)
{
    stage_half(g, ldk, row0, ktile, 0, buf, w, sr, sc);
    stage_half(g, ldk, row0, ktile, 1, buf, w, sr, sc);
}

#define LOAD_AF(DST, BUF, MTB) \
    _Pragma("unroll") for (int mt = 0; mt < 4; ++mt) \
    _Pragma("unroll") for (int ks = 0; ks < 2; ++ks) \
        DST[mt][ks] = *(const bf8v*)((BUF) + (((wm * 8 + (MTB) + mt) * 2 + ks) << 10) + frag_off);
#define LOAD_BF(DST, BUF, NTB) \
    _Pragma("unroll") for (int nt = 0; nt < 2; ++nt) \
    _Pragma("unroll") for (int ks = 0; ks < 2; ++ks) \
        DST[nt][ks] = *(const bf8v*)((BUF) + (((wn * 4 + (NTB) + nt) * 2 + ks) << 10) + frag_off);
#define MFMA_Q(MTB, NTB, AR, BR) \
    __builtin_amdgcn_s_setprio(1); \
    _Pragma("unroll") for (int mt = 0; mt < 4; ++mt) \
    _Pragma("unroll") for (int nt = 0; nt < 2; ++nt) \
    _Pragma("unroll") for (int ks = 0; ks < 2; ++ks) \
        acc[(MTB) + mt][(NTB) + nt] = __builtin_amdgcn_mfma_f32_16x16x32_bf16( \
            AR[mt][ks], BR[nt][ks], acc[(MTB) + mt][(NTB) + nt], 0, 0, 0); \
    __builtin_amdgcn_s_setprio(0);

__global__ __launch_bounds__(512, 2)
void gemm_nt_pl(const __bf16* __restrict__ A, const __bf16* __restrict__ B,
                __bf16* __restrict__ P, int M, int N, int K, int KS)
{
    __shared__ __align__(1024) char lds[131072];
    char* A0 = lds;
    char* A1 = lds + 32768;
    char* B0 = lds + 65536;
    char* B1 = lds + 98304;

    const int tid = threadIdx.x, lane = tid & 63, w = tid >> 6;
    const int wm = w >> 2, wn = w & 3;
    const int mm = lane & 15, quad = lane >> 4;

    // XCD-chunked swizzle (nwg % 8 == 0 for all launches here)
    const int nbx = gridDim.x, nby = gridDim.y;
    int flat = blockIdx.x + nbx * (blockIdx.y + nby * blockIdx.z);
    const int cpx = (nbx * nby * gridDim.z) >> 3;
    flat = (flat & 7) * cpx + (flat >> 3);
    const int bxi = flat % nbx, byi = (flat / nbx) % nby, bzi = flat / (nbx * nby);

    const int m0 = byi * 256, n0 = bxi * 256;
    const int kt0 = (bzi * KS) >> 6;
    const int T = KS >> 6;                          // K-tiles per block (>=4, even)

    const int sr = lane >> 2, sc = (lane & 3) * 8;  // staging lane offsets
    const int frag_off = (mm * 4 + quad) << 4;      // frag read offset in subtile

    f4v acc[8][4] = {};
    bf8v aLo[4][2], aHi[4][2], b01e[2][2], b01o[2][2], b23[2][2];

    // prologue: fully stage tiles kt0 (buf0), kt0+1 (buf1)
    stage_tile(A, K, m0, kt0,     A0, w, sr, sc);
    stage_tile(B, K, n0, kt0,     B0, w, sr, sc);
    stage_tile(A, K, m0, kt0 + 1, A1, w, sr, sc);
    stage_tile(B, K, n0, kt0 + 1, B1, w, sr, sc);
    VMC(8);                                         // drain tile kt0 (oldest 8)
    wgb();
    LOAD_AF(aLo, A0, 0)
    LOAD_BF(b01e, B0, 0)

    const int nbody = (T - 2) >> 1;
    for (int it = 0; it < nbody; ++it) {
        const int t2 = kt0 + 2 * it + 2, t3 = t2 + 1;
        // P1: rd b23(t); MFMA Q1(t)
        LOAD_BF(b23, B0, 2)
        MFMA_Q(0, 0, aLo, b01e)
        wgb();
        // P2: rd aHi(t); MFMA Q2(t) [consumes b23<-B0]; stage B(t+2)->B0;
        //     VMC(4) drains t+1, leaves B(t+2) in flight
        LOAD_AF(aHi, A0, 4)
        MFMA_Q(0, 2, aLo, b23)
        stage_tile(B, K, n0, t2, B0, w, sr, sc);
        VMC(4);
        wgb();
        // P3: rd aLo(t+1); MFMA Q3(t) [consumes aHi<-A0]; stage A(t+2)->A0
        LOAD_AF(aLo, A1, 0)
        MFMA_Q(4, 2, aHi, b23)
        stage_tile(A, K, m0, t2, A0, w, sr, sc);
        wgb();
        // P4: rd b01(t+1); MFMA Q4(t)
        LOAD_BF(b01o, B1, 0)
        MFMA_Q(4, 0, aHi, b01e)
        wgb();
        // P5: rd b23(t+1); MFMA Q1(t+1)
        LOAD_BF(b23, B1, 2)
        MFMA_Q(0, 0, aLo, b01o)
        wgb();
        // P6: rd aHi(t+1); MFMA Q2(t+1) [consumes b23<-B1]; stage B(t+3)->B1;
        //     VMC(4) drains t+2, leaves B(t+3) in flight
        LOAD_AF(aHi, A1, 4)
        MFMA_Q(0, 2, aLo, b23)
        stage_tile(B, K, n0, t3, B1, w, sr, sc);
        VMC(4);
        wgb();
        // P7: rd aLo(t+2); MFMA Q3(t+1) [consumes aHi<-A1]; stage A(t+3)->A1
        LOAD_AF(aLo, A0, 0)
        MFMA_Q(4, 2, aHi, b23)
        stage_tile(A, K, m0, t3, A1, w, sr, sc);
        wgb();
        // P8: rd b01(t+2); MFMA Q4(t+1)
        LOAD_BF(b01e, B0, 0)
        MFMA_Q(4, 0, aHi, b01o)
        wgb();
    }
    // tail: tiles T-2 (buf0), T-1 (buf1); no staging
    LOAD_BF(b23, B0, 2)
    MFMA_Q(0, 0, aLo, b01e)
    wgb();
    LOAD_AF(aHi, A0, 4)
    MFMA_Q(0, 2, aLo, b23)
    VMC(0);
    wgb();
    LOAD_AF(aLo, A1, 0)
    MFMA_Q(4, 2, aHi, b23)
    wgb();
    LOAD_BF(b01o, B1, 0)
    MFMA_Q(4, 0, aHi, b01e)
    wgb();
    LOAD_BF(b23, B1, 2)
    MFMA_Q(0, 0, aLo, b01o)
    wgb();
    LOAD_AF(aHi, A1, 4)
    MFMA_Q(0, 2, aLo, b23)
    wgb();
    MFMA_Q(4, 2, aHi, b23)
    MFMA_Q(4, 0, aHi, b01o)

    __bf16* Pz = P + (size_t)bzi * M * N;
#pragma unroll
    for (int mt = 0; mt < 8; ++mt)
#pragma unroll
        for (int nt = 0; nt < 4; ++nt)
#pragma unroll
            for (int r = 0; r < 4; ++r)
                Pz[(size_t)(m0 + wm * 128 + mt * 16 + quad * 4 + r) * N
                   + n0 + wn * 64 + nt * 16 + mm] = (__bf16)acc[mt][nt][r];
}

// ---- sum 4 bf16 partials -> fp32 out -----------------------------------
__global__ __launch_bounds__(256)
void add4(const __bf16* __restrict__ P, float* __restrict__ out, int n4)
{
    int i = blockIdx.x * 256 + threadIdx.x;
    if (i >= n4) return;
    float4 s = {0.f, 0.f, 0.f, 0.f};
#pragma unroll
    for (int z = 0; z < 4; ++z) {
        bf4v v = *reinterpret_cast<const bf4v*>(P + (size_t)z * n4 * 4 + (size_t)i * 4);
        s.x += (float)v[0]; s.y += (float)v[1]; s.z += (float)v[2]; s.w += (float)v[3];
    }
    *reinterpret_cast<float4*>(out + (size_t)i * 4) = s;
}

// ---- norm_rope fused with K-pack AND V-pack ----------------------------
__global__ __launch_bounds__(256)
void norm_rope_pk(__bf16* __restrict__ qkv /* p0, q in place */,
                  const __bf16* __restrict__ p1,
                  const float* __restrict__ qw, const float* __restrict__ kw,
                  __bf16* __restrict__ Kt, __bf16* __restrict__ Vt)
{
    const int s = blockIdx.x, hh = blockIdx.y * 4 + threadIdx.y, l = threadIdx.x;
    if (hh >= NH + NKV) {                          // ---- V path ----
        const int vh = hh - (NH + NKV);
        const int off = 2560 + vh * HD;
        const __bf16* p  = qkv + (size_t)s * QS + off;
        const __bf16* q1 = p1  + (size_t)s * QS + off;
        float x0 = (float)p[l]      + (float)q1[l];
        float x1 = (float)p[l + 64] + (float)q1[l + 64];
        char* tile = (char*)Vt + (size_t)(vh * 32 + (s >> 6)) * 16384;
        const int kc = (s >> 3) & 7, j = s & 7;
        const int d2 = l + 64;
        *reinterpret_cast<__bf16*>(tile + l  * 128 + ((kc ^ (l  & 7)) << 4) + j * 2) = (__bf16)x0;
        *reinterpret_cast<__bf16*>(tile + d2 * 128 + ((kc ^ (d2 & 7)) << 4) + j * 2) = (__bf16)x1;
        return;
    }
    const float* wn; float scale; int off;
    if (hh < NH) { off = hh * HD;               wn = qw; scale = 0.08838834764831845f; }
    else         { off = 2048 + (hh - NH) * HD; wn = kw; scale = 1.0f; }
    __bf16* p = qkv + (size_t)s * QS + off;
    const __bf16* q1 = p1 + (size_t)s * QS + off;
    float x0 = (float)p[l]      + (float)q1[l];
    float x1 = (float)p[l + 64] + (float)q1[l + 64];
    float ss = x0 * x0 + x1 * x1;
#pragma unroll
    for (int o = 32; o; o >>= 1) ss += __shfl_xor(ss, o);
    float inv = rsqrtf(ss * (1.0f / 128.0f) + 1e-6f);
    x0 *= inv * wn[l];
    x1 *= inv * wn[l + 64];
    float invf = exp2f(-(float)l * (13.287712379549449f / 64.0f));
    float ang  = (float)s * invf;
    float c, sn;
    sincosf(ang, &sn, &c);
    float y0 = (x0 * c - x1 * sn) * scale;
    float y1 = (x1 * c + x0 * sn) * scale;
    if (hh < NH) {
        p[l]      = (__bf16)y0;
        p[l + 64] = (__bf16)y1;
    } else {
        const int kh = hh - NH, key = s & 63;
        char* tile = (char*)Kt + (size_t)(kh * 32 + (s >> 6)) * 16384 + key * 256;
        const int sw = (key & 15) << 4;
        *reinterpret_cast<__bf16*>(tile + ((((l)      >> 3) << 4) ^ sw) + (l & 7) * 2) = (__bf16)y0;
        *reinterpret_cast<__bf16*>(tile + ((((l + 64) >> 3) << 4) ^ sw) + (l & 7) * 2) = (__bf16)y1;
    }
}

// ---- split-K MFMA flash attention, static-max softmax ------------------
// R11: statically balanced job pairing. Per head, 16 blocks:
//   j<8 : job0 {qt=j,   c=0, tt 0..j}   + job1 {qt=15-j, c=1, tt 8..15-j}
//         -> (j+1) + (8-j) = 9 units
//   j>=8: job0 {qt=j,   c=0, tt 0..7}   -> 8 units
// 256 blocks total = exactly 1/CU, max 9 units (vs R9's uneven 1..8 over
// 384 workers + 128 no-ops). Chunk layout (c in {0,1}, 1024 kv rows) and
// the per-unit inner body are R9-verified and unchanged.
__global__ __launch_bounds__(512)
void attn_split(const __bf16* __restrict__ qkv,
                const __bf16* __restrict__ Kt, const __bf16* __restrict__ Vt,
                __bf16* __restrict__ Op, float* __restrict__ Lp)
{
    __shared__ char Ks[32768];
    __shared__ char Vs[32768];
    __shared__ char Ps[8][2048];

    int flat = blockIdx.x;                          // 256 blocks
    flat = (flat & 7) * 32 + (flat >> 3);           // XCD-chunked (256%8==0)
    const int h = flat >> 4, j = flat & 15;
    const int kh = h >> 2;

    const int tid = threadIdx.x, lane = tid & 63, w = tid >> 6;
    const int mm = lane & 15, quad = lane >> 4;

    const char* kbase = (const char*)Kt + (size_t)(kh * 32) * 16384;
    const char* vbase = (const char*)Vt + (size_t)(kh * 32) * 16384;

    const int njobs = (j < 8) ? 2 : 1;
    for (int job = 0; job < njobs; ++job) {
        int qt, c, t0, t1;
        if (job == 0) { qt = j;      c = 0; t0 = 0; t1 = min(qt, 7); }
        else          { qt = 15 - j; c = 1; t0 = 8; t1 = qt; }       // qt >= 8

        bf8v aq[4];
        const __bf16* qbase = qkv + (size_t)(qt * 128 + w * 16 + mm) * QS + h * HD;
#pragma unroll
        for (int ks = 0; ks < 4; ++ks)
            aq[ks] = *reinterpret_cast<const bf8v*>(qbase + ks * 32 + quad * 8);

        float lp[4] = {};
        f4v oacc[8] = {};

        for (int tt = t0; tt <= t1; ++tt) {
            wgb();                                  // prev compute done (WAR)
#pragma unroll
            for (int jj = 0; jj < 4; ++jj) {
                int chunk = w * 4 + jj;             // 32 chunks = 2 sub-tiles
                gld16(kbase + (size_t)tt * 32768 + chunk * 1024 + lane * 16,
                      Ks + chunk * 1024);
                gld16(vbase + (size_t)tt * 32768 + chunk * 1024 + lane * 16,
                      Vs + chunk * 1024);
            }
            VMC(0);
            wgb();

            const int nss = (tt == qt && w < 4) ? 1 : 2; // skip masked sub
            for (int ss = 0; ss < nss; ++ss) {
                const char* Ksub = Ks + ss * 16384;
                const char* Vsub = Vs + ss * 16384;

                f4v s[4] = {};
#pragma unroll
                for (int ks = 0; ks < 4; ++ks)
#pragma unroll
                    for (int c16 = 0; c16 < 4; ++c16) {
                        bf8v b = *reinterpret_cast<const bf8v*>(
                            Ksub + (c16 * 16 + mm) * 256 + (((ks * 4 + quad) ^ mm) << 4));
                        s[c16] = __builtin_amdgcn_mfma_f32_16x16x32_bf16(aq[ks], b, s[c16], 0, 0, 0);
                    }
                if (tt == qt) {
#pragma unroll
                    for (int c16 = 0; c16 < 4; ++c16)
#pragma unroll
                        for (int r = 0; r < 4; ++r)
                            if (ss * 64 + c16 * 16 + mm > w * 16 + quad * 4 + r)
                                s[c16][r] = -__builtin_inff();
                }
                float pr[4][4];
#pragma unroll
                for (int c16 = 0; c16 < 4; ++c16)
#pragma unroll
                    for (int r = 0; r < 4; ++r) {
                        pr[c16][r] = __expf(s[c16][r]);
                        lp[r] += pr[c16][r];
                    }
#pragma unroll
                for (int c16 = 0; c16 < 4; ++c16)
#pragma unroll
                    for (int r = 0; r < 4; ++r) {
                        float mine  = pr[c16][r];
                        float other = __shfl_xor(mine, 1);
                        if ((mm & 1) == 0) {
                            int roww = quad * 4 + r;
                            int cc   = c16 * 2 + (mm >> 3);
                            *reinterpret_cast<bf2v*>(
                                &Ps[w][roww * 128 + ((cc ^ (roww & 7)) << 4) + (mm & 7) * 2]) =
                                bf2v{ (__bf16)mine, (__bf16)other };
                        }
                    }
                bf8v pa[2];
#pragma unroll
                for (int kb = 0; kb < 2; ++kb)
                    pa[kb] = *reinterpret_cast<const bf8v*>(
                        &Ps[w][mm * 128 + (((kb * 4 + quad) ^ (mm & 7)) << 4)]);
#pragma unroll
                for (int nb = 0; nb < 8; ++nb) {
                    int d = nb * 16 + mm;
#pragma unroll
                    for (int kb = 0; kb < 2; ++kb) {
                        bf8v bv = *reinterpret_cast<const bf8v*>(
                            Vsub + d * 128 + (((kb * 4 + quad) ^ (d & 7)) << 4));
                        oacc[nb] = __builtin_amdgcn_mfma_f32_16x16x32_bf16(pa[kb], bv, oacc[nb], 0, 0, 0);
                    }
                }
            }
        }
#pragma unroll
        for (int off = 1; off < 16; off <<= 1)
#pragma unroll
            for (int r = 0; r < 4; ++r) lp[r] += __shfl_xor(lp[r], off);
#pragma unroll
        for (int r = 0; r < 4; ++r) {
            int row = qt * 128 + w * 16 + quad * 4 + r;
            size_t obase = ((size_t)(c * 16 + h) * SEQ + row) * HD;
#pragma unroll
            for (int nb = 0; nb < 8; ++nb)
                Op[obase + nb * 16 + mm] = (__bf16)oacc[nb][r];
            if (mm == 0)
                Lp[(size_t)(c * 16 + h) * SEQ + row] = lp[r];
        }
    }
}

// ---- combine split-K partials -> ab (bf16 [row][h*128+d]) --------------
__global__ __launch_bounds__(256)
void combine(const __bf16* __restrict__ Op, const float* __restrict__ Lp,
             __bf16* __restrict__ ab)
{
    const int row = blockIdx.x, h = blockIdx.y * 4 + threadIdx.y, l = threadIdx.x;
    const int nch = (row >> 10) + 1;               // 1024 kv rows per chunk
    float L = 0.f, a0 = 0.f, a1 = 0.f;
    for (int c = 0; c < nch; ++c) {
        L += Lp[(size_t)(c * 16 + h) * SEQ + row];
        bf2v p = *reinterpret_cast<const bf2v*>(
            Op + ((size_t)(c * 16 + h) * SEQ + row) * HD + 2 * l);
        a0 += (float)p[0];
        a1 += (float)p[1];
    }
    float inv = 1.f / L;
    *reinterpret_cast<bf2v*>(ab + (size_t)row * (NH * HD) + h * HD + 2 * l) =
        bf2v{ (__bf16)(a0 * inv), (__bf16)(a1 * inv) };
}

extern "C" void kernel_launch(void* const* d_in, const int* in_sizes, int n_in,
                              void* d_out, int out_size, void* d_ws, size_t ws_size,
                              hipStream_t stream)
{
    const float* hs  = (const float*)d_in[0];
    const float* mu  = (const float*)d_in[1];
    const float* wq  = (const float*)d_in[2];
    const float* wk  = (const float*)d_in[3];
    const float* wv  = (const float*)d_in[4];
    const float* wo  = (const float*)d_in[5];
    const float* wmq = (const float*)d_in[6];
    const float* wmk = (const float*)d_in[7];
    const float* wmv = (const float*)d_in[8];
    const float* qw  = (const float*)d_in[9];
    const float* kw  = (const float*)d_in[10];
    float* out = (float*)d_out;

    char* ws = (char*)d_ws;
    // phase 1 (projection):
    __bf16* Wcat = (__bf16*)(ws + 0);          // [3072,4096] 25.2 MB
    __bf16* Acat = (__bf16*)(ws + 25165824);   // [2048,4096] 16.8 MB
    __bf16* Wo   = (__bf16*)(ws + 41943040);   // [2048,2048]  8.4 MB
    __bf16* qkvp = (__bf16*)(ws + 50331648);   // 2x[2048,3072] bf16 partials
    __bf16* ab   = (__bf16*)(ws + 75497472);   // [2048,2048] bf16, peak 83.9 MB
    // phase 2 aliases (Wcat/Acat dead after QKV GEMM):
    __bf16* Ktl  = (__bf16*)(ws + 0);          // 2 MB
    __bf16* Vtl  = (__bf16*)(ws + 2097152);    // 2 MB
    __bf16* Opart= (__bf16*)(ws + 4194304);    // 2x16 chunk-images = 16.8 MB
    float*  Lpart= (float*) (ws + 37748736);   // 0.25 MB
    // phase 3 alias (attn scratch dead after combine):
    __bf16* outp = (__bf16*)(ws + 0);          // 4x[2048,2048] bf16 = 33.6 MB

    // single fused convert pass
    cvt_all<<<dim3(24576), 256, 0, stream>>>(Acat, Wcat, Wo,
                                             hs, mu, wq, wmq, wk, wmk, wv, wmv, wo);

    // QKV projection: 256^2 pipelined, split-K=2 -> 192 blocks (bf16 partials)
    gemm_nt_pl<<<dim3(QS / 256, SEQ / 256, 2), 512, 0, stream>>>(
        Acat, Wcat, qkvp, SEQ, QS, 2 * HID_DIM, HID_DIM);
    // norm+rope; q in place, k packed into Ktl, v packed into Vtl (all fused)
    norm_rope_pk<<<dim3(SEQ, 6), dim3(64, 4), 0, stream>>>(
        qkvp, qkvp + (size_t)SEQ * QS, qw, kw, Ktl, Vtl);
    // attention: 256 balanced blocks (1/CU), 8-9 units each, chunk=1024
    attn_split<<<dim3(256), 512, 0, stream>>>(qkvp, Ktl, Vtl, Opart, Lpart);
    combine<<<dim3(SEQ, 4), dim3(64, 4), 0, stream>>>(Opart, Lpart, ab);
    // output projection: split-K=4 -> 256 blocks, bf16 partials + add pass
    gemm_nt_pl<<<dim3(HID_DIM / 256, SEQ / 256, 4), 512, 0, stream>>>(
        ab, Wo, outp, SEQ, HID_DIM, NH * HD, 512);
    add4<<<dim3((1024 * 1024 + 255) / 256), 256, 0, stream>>>(outp, out, 1024 * 1024);
}